// Round 1
// baseline (347.556 us; speedup 1.0000x reference)
//
#include <hip/hip_runtime.h>
#include <hip/hip_bf16.h>

typedef __attribute__((ext_vector_type(4))) float f32x4_t;
typedef __attribute__((ext_vector_type(8))) short bf16x8_t;

__device__ __forceinline__ short f2bfs(float x) {
    union { __hip_bfloat16 h; short s; } u;
    u.h = __float2bfloat16(x);   // RNE
    return u.s;
}

// ---------------------------------------------------------------------------
// Kernel 1: build fused 512x512 operator M in fragment-major bf16 layout.
//   c = m*32+o (output col of GEMM), k = n2*32+f (contraction index)
//   M[c][k] = diag[m] * sum_{n,m2} basis[m,n] * Wbig[o,n,f,m2] * basis[n2,m2]
// Fragment layout for mfma_f32_16x16x32_bf16 B-operand:
//   frag(ks, c16): lane = (c&15) + 16*g, elem j; value = M[c16*16 + (c&15)][ks*32 + g*8 + j]
//   flat ushort idx = ((ks*32 + c16)*64 + lane)*8 + j
// ---------------------------------------------------------------------------
__global__ void build_M_kernel(const float* __restrict__ basis,
                               const float* __restrict__ adj,
                               const float* __restrict__ e,
                               const float* __restrict__ We,
                               const float* __restrict__ W2,
                               const float* __restrict__ W3,
                               unsigned short* __restrict__ Mfrag) {
    const int t = blockIdx.x * blockDim.x + threadIdx.x;  // 0..262143
    const int c = t >> 9;           // 0..511
    const int k = t & 511;
    const int m  = c >> 5, o = c & 31;
    const int n2 = k >> 5, f = k & 31;

    // diag[m] = softmax(row m of masked logits)[m]
    float lv[16];
    float mx = -3.4e38f;
#pragma unroll
    for (int j = 0; j < 16; ++j) {
        float a = adj[m * 16 + j];
        float v = (a > 0.0f) ? e[m * 16 + j] : -9.0e15f;
        lv[j] = v;
        mx = fmaxf(mx, v);
    }
    float s = 0.0f;
#pragma unroll
    for (int j = 0; j < 16; ++j) s += expf(lv[j] - mx);
    const float dg = expf(lv[m] - mx) / s;

    float acc = 0.0f;
#pragma unroll
    for (int n = 0; n < 10; ++n) {
        float t2 = 0.0f;
#pragma unroll
        for (int m2 = 0; m2 < 10; ++m2)
            t2 += We[(o * 10 + n) * 320 + f * 10 + m2] * basis[n2 * 16 + m2];
        acc += basis[m * 16 + n] * t2;
    }
#pragma unroll
    for (int n = 0; n < 3; ++n) {
        float t2 = 0.0f;
#pragma unroll
        for (int m2 = 0; m2 < 3; ++m2)
            t2 += W2[(o * 3 + n) * 96 + f * 3 + m2] * basis[n2 * 16 + 10 + m2];
        acc += basis[m * 16 + 10 + n] * t2;
    }
#pragma unroll
    for (int n = 0; n < 3; ++n) {
        float t2 = 0.0f;
#pragma unroll
        for (int m2 = 0; m2 < 3; ++m2)
            t2 += W3[(o * 3 + n) * 96 + f * 3 + m2] * basis[n2 * 16 + 13 + m2];
        acc += basis[m * 16 + 13 + n] * t2;
    }

    const float Mv = dg * acc;

    const int ks = k >> 5;
    const int g  = (k >> 3) & 3;
    const int j  = k & 7;
    const int idx = ((ks * 32 + (c >> 4)) * 64 + ((c & 15) + 16 * g)) * 8 + j;
    Mfrag[idx] = (unsigned short)f2bfs(Mv);
}

// ---------------------------------------------------------------------------
// Kernel 2: Y[131072 x 512] = X[131072 x 512] @ M^T + bias
// Block: 512 threads (8 waves). Block tile: 64 rows x 512 cols (full N -> X
// read once from HBM; all 8 waves read identical A addresses -> L1 hits).
// Wave tile: 64 rows x 64 cols -> acc 4x4 frags of 16x16, K-loop 16 steps of 32.
// B-fragments loaded directly from L2-resident Mfrag (no LDS). Register
// ping-pong prefetch of the next K-step.
// ---------------------------------------------------------------------------
__global__ __launch_bounds__(512, 2)
void gemm_kernel(const float* __restrict__ X,
                 const unsigned short* __restrict__ Mfrag,
                 const float* __restrict__ bias,
                 float* __restrict__ Y) {
    const int tid  = threadIdx.x;
    const int lane = tid & 63;
    const int wave = tid >> 6;        // 0..7
    const int l15  = lane & 15;
    const int g    = lane >> 4;       // 0..3
    const size_t rowbase = (size_t)blockIdx.x * 64;
    const int    colbase = wave * 64;

    // A: lane reads x[row = rowbase + mi*16 + l15, k = ks*32 + g*8 + j]
    const float* xp = X + (rowbase + l15) * 512 + g * 8;
    // B: frag (ks, c16 = colbase/16 + ni) at ushort offset ((ks*32+c16)*64+lane)*8
    const unsigned short* bp = Mfrag + ((size_t)((colbase >> 4) * 64) + lane) * 8;

    f32x4_t acc[4][4];
#pragma unroll
    for (int a = 0; a < 4; ++a)
#pragma unroll
        for (int b = 0; b < 4; ++b)
            acc[a][b] = (f32x4_t){0.f, 0.f, 0.f, 0.f};

    f32x4_t   Ar[2][4][2];
    bf16x8_t  Bf[2][4];

#pragma unroll
    for (int mi = 0; mi < 4; ++mi) {
        const float* p = xp + mi * (16 * 512);
        Ar[0][mi][0] = *reinterpret_cast<const f32x4_t*>(p);
        Ar[0][mi][1] = *reinterpret_cast<const f32x4_t*>(p + 4);
    }
#pragma unroll
    for (int ni = 0; ni < 4; ++ni)
        Bf[0][ni] = *reinterpret_cast<const bf16x8_t*>(bp + ni * 512);

#pragma unroll
    for (int ks = 0; ks < 16; ++ks) {
        const int cur = ks & 1, nxt = cur ^ 1;
        if (ks < 15) {
            const float* p2 = xp + (ks + 1) * 32;
#pragma unroll
            for (int mi = 0; mi < 4; ++mi) {
                Ar[nxt][mi][0] = *reinterpret_cast<const f32x4_t*>(p2 + mi * (16 * 512));
                Ar[nxt][mi][1] = *reinterpret_cast<const f32x4_t*>(p2 + mi * (16 * 512) + 4);
            }
            const unsigned short* b2 = bp + (size_t)(ks + 1) * (32 * 64 * 8);
#pragma unroll
            for (int ni = 0; ni < 4; ++ni)
                Bf[nxt][ni] = *reinterpret_cast<const bf16x8_t*>(b2 + ni * 512);
        }

        bf16x8_t a[4];
#pragma unroll
        for (int mi = 0; mi < 4; ++mi) {
#pragma unroll
            for (int jj = 0; jj < 4; ++jj) {
                a[mi][jj]     = f2bfs(Ar[cur][mi][0][jj]);
                a[mi][jj + 4] = f2bfs(Ar[cur][mi][1][jj]);
            }
        }
#pragma unroll
        for (int mi = 0; mi < 4; ++mi)
#pragma unroll
            for (int ni = 0; ni < 4; ++ni)
                acc[mi][ni] = __builtin_amdgcn_mfma_f32_16x16x32_bf16(
                    a[mi], Bf[cur][ni], acc[mi][ni], 0, 0, 0);
    }

    // Epilogue. C/D layout (HW-verified): col = lane&15, row = (lane>>4)*4 + reg.
    // o = col & 31; colbase is a multiple of 64, so o = (ni&1)*16 + l15.
    const float b_lo = bias[l15];
    const float b_hi = bias[16 + l15];

#pragma unroll
    for (int mi = 0; mi < 4; ++mi) {
#pragma unroll
        for (int ni = 0; ni < 4; ++ni) {
            const float bb  = (ni & 1) ? b_hi : b_lo;
            const size_t row0 = rowbase + mi * 16 + g * 4;
            const int    col  = colbase + ni * 16 + l15;
            float* yp = Y + row0 * 512 + col;
#pragma unroll
            for (int r = 0; r < 4; ++r)
                yp[(size_t)r * 512] = acc[mi][ni][r] + bb;
        }
    }
}

extern "C" void kernel_launch(void* const* d_in, const int* in_sizes, int n_in,
                              void* d_out, int out_size, void* d_ws, size_t ws_size,
                              hipStream_t stream) {
    const float* x     = (const float*)d_in[0];
    const float* basis = (const float*)d_in[1];
    const float* adj   = (const float*)d_in[2];
    const float* e     = (const float*)d_in[3];
    const float* We    = (const float*)d_in[4];
    const float* W2    = (const float*)d_in[5];
    const float* W3    = (const float*)d_in[6];
    const float* bias  = (const float*)d_in[7];

    unsigned short* Mfrag = (unsigned short*)d_ws;  // 512 KB needed
    if (ws_size < 512u * 512u * 2u) return;

    const int Bsz = in_sizes[0] / 512;              // 131072
    build_M_kernel<<<512, 512, 0, stream>>>(basis, adj, e, We, W2, W3, Mfrag);
    gemm_kernel<<<Bsz / 64, 512, 0, stream>>>(x, Mfrag, bias, (float*)d_out);
}

// Round 2
// 160.713 us; speedup vs baseline: 2.1626x; 2.1626x over previous
//
#include <hip/hip_runtime.h>
#include <hip/hip_bf16.h>

typedef __attribute__((ext_vector_type(4))) float f32x4_t;
typedef __attribute__((ext_vector_type(8))) short bf16x8_t;

__device__ __forceinline__ short f2bfs(float x) {
    union { __hip_bfloat16 h; short s; } u;
    u.h = __float2bfloat16(x);   // RNE
    return u.s;
}

// ---------------------------------------------------------------------------
// Kernel 1: build fused 512x512 operator M in fragment-major bf16 layout.
//   c = m*32+o (output col of GEMM), k = n2*32+f (contraction index)
//   M[c][k] = diag[m] * sum_{n,m2} basis[m,n] * Wbig[o,n,f,m2] * basis[n2,m2]
// B-fragment layout for mfma_f32_16x16x32_bf16:
//   flat ushort idx = ((ks*32 + c16)*64 + lane)*8 + j
//   value = M[c16*16 + (lane&15)][ks*32 + (lane>>4)*8 + j]
// ---------------------------------------------------------------------------
__global__ void build_M_kernel(const float* __restrict__ basis,
                               const float* __restrict__ adj,
                               const float* __restrict__ e,
                               const float* __restrict__ We,
                               const float* __restrict__ W2,
                               const float* __restrict__ W3,
                               unsigned short* __restrict__ Mfrag) {
    const int t = blockIdx.x * blockDim.x + threadIdx.x;  // 0..262143
    const int c = t >> 9;           // 0..511
    const int k = t & 511;
    const int m  = c >> 5, o = c & 31;
    const int n2 = k >> 5, f = k & 31;

    // diag[m] = softmax(row m of masked logits)[m]
    float lv[16];
    float mx = -3.4e38f;
#pragma unroll
    for (int j = 0; j < 16; ++j) {
        float a = adj[m * 16 + j];
        float v = (a > 0.0f) ? e[m * 16 + j] : -9.0e15f;
        lv[j] = v;
        mx = fmaxf(mx, v);
    }
    float s = 0.0f;
#pragma unroll
    for (int j = 0; j < 16; ++j) s += expf(lv[j] - mx);
    const float dg = expf(lv[m] - mx) / s;

    float acc = 0.0f;
#pragma unroll
    for (int n = 0; n < 10; ++n) {
        float t2 = 0.0f;
#pragma unroll
        for (int m2 = 0; m2 < 10; ++m2)
            t2 += We[(o * 10 + n) * 320 + f * 10 + m2] * basis[n2 * 16 + m2];
        acc += basis[m * 16 + n] * t2;
    }
#pragma unroll
    for (int n = 0; n < 3; ++n) {
        float t2 = 0.0f;
#pragma unroll
        for (int m2 = 0; m2 < 3; ++m2)
            t2 += W2[(o * 3 + n) * 96 + f * 3 + m2] * basis[n2 * 16 + 10 + m2];
        acc += basis[m * 16 + 10 + n] * t2;
    }
#pragma unroll
    for (int n = 0; n < 3; ++n) {
        float t2 = 0.0f;
#pragma unroll
        for (int m2 = 0; m2 < 3; ++m2)
            t2 += W3[(o * 3 + n) * 96 + f * 3 + m2] * basis[n2 * 16 + 13 + m2];
        acc += basis[m * 16 + 13 + n] * t2;
    }

    const float Mv = dg * acc;

    const int ks = k >> 5;
    const int g  = (k >> 3) & 3;
    const int j  = k & 7;
    const int idx = ((ks * 32 + (c >> 4)) * 64 + ((c & 15) + 16 * g)) * 8 + j;
    Mfrag[idx] = (unsigned short)f2bfs(Mv);
}

// ---------------------------------------------------------------------------
// Kernel 2: Y[131072 x 512] = X[131072 x 512] @ M^T + bias
// Block: 512 threads (8 waves), block tile 64 rows x 512 cols.
// Phase A: cooperative stage of the 64x512 f32 X-tile -> bf16 A-fragments in
//   LDS (64 KB), lane-linear ds_write_b128 (conflict-free). All 16 global
//   loads per thread issue before the barrier -> deep HBM queue.
// Phase B: K-loop, A from LDS (ds_read_b128, conflict-free), B from
//   L2-resident Mfrag, 16 MFMAs per K-step per wave.
// __launch_bounds__(512,4): target 2 blocks/CU so staging overlaps compute.
// ---------------------------------------------------------------------------
__global__ __launch_bounds__(512, 4)
void gemm_kernel(const float* __restrict__ X,
                 const unsigned short* __restrict__ Mfrag,
                 const float* __restrict__ bias,
                 float* __restrict__ Y) {
    __shared__ unsigned short Albs[16 * 4 * 64 * 8];   // [ks][mi][lane][8] bf16, 64 KB

    const int tid  = threadIdx.x;
    const int lane = tid & 63;
    const int wave = tid >> 6;        // 0..7
    const int l15  = lane & 15;
    const int g    = lane >> 4;       // 0..3
    const size_t rowbase = (size_t)blockIdx.x * 64;

    // ---- Phase A: stage X-tile as bf16 fragments ----
    {
        const float* xb = X + rowbase * 512;
#pragma unroll
        for (int c = 0; c < 8; ++c) {
            const int p  = c * 8 + wave;        // 0..63 = (ks,mi)
            const int ks = p >> 2, mi = p & 3;
            const int row = mi * 16 + l15;
            const int k0  = ks * 32 + g * 8;
            const float* src = xb + row * 512 + k0;
            f32x4_t v0 = __builtin_nontemporal_load(reinterpret_cast<const f32x4_t*>(src));
            f32x4_t v1 = __builtin_nontemporal_load(reinterpret_cast<const f32x4_t*>(src + 4));
            bf16x8_t bv;
#pragma unroll
            for (int j = 0; j < 4; ++j) {
                bv[j]     = f2bfs(v0[j]);
                bv[j + 4] = f2bfs(v1[j]);
            }
            *reinterpret_cast<bf16x8_t*>(&Albs[(p * 64 + lane) * 8]) = bv;
        }
    }
    __syncthreads();

    // ---- Phase B: K-loop ----
    const int colbase = wave * 64;
    const unsigned short* bp = Mfrag + ((size_t)((colbase >> 4) * 64) + lane) * 8;

    f32x4_t acc[4][4];
#pragma unroll
    for (int a = 0; a < 4; ++a)
#pragma unroll
        for (int b = 0; b < 4; ++b)
            acc[a][b] = (f32x4_t){0.f, 0.f, 0.f, 0.f};

#pragma unroll
    for (int ks = 0; ks < 16; ++ks) {
        bf16x8_t a[4], bfr[4];
#pragma unroll
        for (int mi = 0; mi < 4; ++mi)
            a[mi] = *reinterpret_cast<const bf16x8_t*>(&Albs[((ks * 4 + mi) * 64 + lane) * 8]);
#pragma unroll
        for (int ni = 0; ni < 4; ++ni)
            bfr[ni] = *reinterpret_cast<const bf16x8_t*>(bp + ks * 16384 + ni * 512);
#pragma unroll
        for (int mi = 0; mi < 4; ++mi)
#pragma unroll
            for (int ni = 0; ni < 4; ++ni)
                acc[mi][ni] = __builtin_amdgcn_mfma_f32_16x16x32_bf16(
                    a[mi], bfr[ni], acc[mi][ni], 0, 0, 0);
    }

    // ---- Epilogue: bias + nontemporal stores ----
    // C/D layout: col = lane&15, row = (lane>>4)*4 + reg.
    const float b_lo = bias[l15];
    const float b_hi = bias[16 + l15];

#pragma unroll
    for (int mi = 0; mi < 4; ++mi) {
#pragma unroll
        for (int ni = 0; ni < 4; ++ni) {
            const float bb  = (ni & 1) ? b_hi : b_lo;
            const size_t row0 = rowbase + mi * 16 + g * 4;
            const int    col  = colbase + ni * 16 + l15;
            float* yp = Y + row0 * 512 + col;
#pragma unroll
            for (int r = 0; r < 4; ++r)
                __builtin_nontemporal_store(acc[mi][ni][r] + bb, yp + (size_t)r * 512);
        }
    }
}

extern "C" void kernel_launch(void* const* d_in, const int* in_sizes, int n_in,
                              void* d_out, int out_size, void* d_ws, size_t ws_size,
                              hipStream_t stream) {
    const float* x     = (const float*)d_in[0];
    const float* basis = (const float*)d_in[1];
    const float* adj   = (const float*)d_in[2];
    const float* e     = (const float*)d_in[3];
    const float* We    = (const float*)d_in[4];
    const float* W2    = (const float*)d_in[5];
    const float* W3    = (const float*)d_in[6];
    const float* bias  = (const float*)d_in[7];

    unsigned short* Mfrag = (unsigned short*)d_ws;  // 512 KB needed
    if (ws_size < 512u * 512u * 2u) return;

    const int Bsz = in_sizes[0] / 512;              // 131072
    build_M_kernel<<<512, 512, 0, stream>>>(basis, adj, e, We, W2, W3, Mfrag);
    gemm_kernel<<<Bsz / 64, 512, 0, stream>>>(x, Mfrag, bias, (float*)d_out);
}

// Round 3
// 140.813 us; speedup vs baseline: 2.4682x; 1.1413x over previous
//
#include <hip/hip_runtime.h>
#include <hip/hip_bf16.h>

typedef __attribute__((ext_vector_type(4))) float f32x4_t;
typedef __attribute__((ext_vector_type(8))) short bf16x8_t;

__device__ __forceinline__ short f2bfs(float x) {
    union { __hip_bfloat16 h; short s; } u;
    u.h = __float2bfloat16(x);   // RNE
    return u.s;
}

__device__ __forceinline__ void gload_lds16(const float* g, float* l) {
    __builtin_amdgcn_global_load_lds(
        (const __attribute__((address_space(1))) void*)g,
        (__attribute__((address_space(3))) void*)l, 16, 0, 0);
}

// ---------------------------------------------------------------------------
// Kernel 1: build fused 512x512 operator M in fragment-major bf16 layout.
//   c = m*32+o (output col of GEMM), k = n2*32+f (contraction index)
//   M[c][k] = diag[m] * sum_{n,m2} basis[m,n] * Wbig[o,n,f,m2] * basis[n2,m2]
// B-fragment layout for mfma_f32_16x16x32_bf16:
//   flat ushort idx = ((ks*32 + c16)*64 + lane)*8 + j
//   value = M[c16*16 + (lane&15)][ks*32 + (lane>>4)*8 + j]
// ---------------------------------------------------------------------------
__global__ void build_M_kernel(const float* __restrict__ basis,
                               const float* __restrict__ adj,
                               const float* __restrict__ e,
                               const float* __restrict__ We,
                               const float* __restrict__ W2,
                               const float* __restrict__ W3,
                               unsigned short* __restrict__ Mfrag) {
    const int t = blockIdx.x * blockDim.x + threadIdx.x;  // 0..262143
    const int c = t >> 9;           // 0..511
    const int k = t & 511;
    const int m  = c >> 5, o = c & 31;
    const int n2 = k >> 5, f = k & 31;

    float lv[16];
    float mx = -3.4e38f;
#pragma unroll
    for (int j = 0; j < 16; ++j) {
        float a = adj[m * 16 + j];
        float v = (a > 0.0f) ? e[m * 16 + j] : -9.0e15f;
        lv[j] = v;
        mx = fmaxf(mx, v);
    }
    float s = 0.0f;
#pragma unroll
    for (int j = 0; j < 16; ++j) s += expf(lv[j] - mx);
    const float dg = expf(lv[m] - mx) / s;

    float acc = 0.0f;
#pragma unroll
    for (int n = 0; n < 10; ++n) {
        float t2 = 0.0f;
#pragma unroll
        for (int m2 = 0; m2 < 10; ++m2)
            t2 += We[(o * 10 + n) * 320 + f * 10 + m2] * basis[n2 * 16 + m2];
        acc += basis[m * 16 + n] * t2;
    }
#pragma unroll
    for (int n = 0; n < 3; ++n) {
        float t2 = 0.0f;
#pragma unroll
        for (int m2 = 0; m2 < 3; ++m2)
            t2 += W2[(o * 3 + n) * 96 + f * 3 + m2] * basis[n2 * 16 + 10 + m2];
        acc += basis[m * 16 + 10 + n] * t2;
    }
#pragma unroll
    for (int n = 0; n < 3; ++n) {
        float t2 = 0.0f;
#pragma unroll
        for (int m2 = 0; m2 < 3; ++m2)
            t2 += W3[(o * 3 + n) * 96 + f * 3 + m2] * basis[n2 * 16 + 13 + m2];
        acc += basis[m * 16 + 13 + n] * t2;
    }

    const float Mv = dg * acc;

    const int ks = k >> 5;
    const int g  = (k >> 3) & 3;
    const int j  = k & 7;
    const int idx = ((ks * 32 + (c >> 4)) * 64 + ((c & 15) + 16 * g)) * 8 + j;
    Mfrag[idx] = (unsigned short)f2bfs(Mv);
}

// ---------------------------------------------------------------------------
// Kernel 2: Y[131072 x 512] = X[131072 x 512] @ M^T + bias
// Block: 512 threads (8 waves), block tile 32 rows x 512 cols, grid 4096.
// Stage: X-tile (32x512 f32, 64 KB) via global_load_lds width-16 DMA —
//   no VGPR round-trip, async, 8 instrs/wave. LDS k-index XOR-swizzled
//   (k4 ^ row&7) via pre-swizzled GLOBAL source (dest stays lane-linear).
// K-loop: A = ds_read_b128 x2 + cvt->bf16 (swizzle kills the 16-way
//   bank conflict); B = bf16 fragments from L2-resident Mfrag. 8 MFMA/ks.
// Epilogue: per-wave transpose through LDS (reuse A region after barrier),
//   NT dwordx4 stores -> 256B contiguous segments per 16 lanes.
// ---------------------------------------------------------------------------
__global__ __launch_bounds__(512, 4)
void gemm_kernel(const float* __restrict__ X,
                 const unsigned short* __restrict__ Mfrag,
                 const float* __restrict__ bias,
                 float* __restrict__ Y) {
    __shared__ float Atile[32 * 512];   // 64 KB

    const int tid  = threadIdx.x;
    const int lane = tid & 63;
    const int wave = tid >> 6;        // 0..7
    const int l15  = lane & 15;
    const int g    = lane >> 4;       // 0..3
    const size_t rowbase = (size_t)blockIdx.x * 32;

    // ---- Stage: 8 async DMA loads per wave, 1 KB each ----
    {
        const float* xb = X + rowbase * 512;
#pragma unroll
        for (int i = 0; i < 8; ++i) {
            const int row  = wave * 4 + (i >> 1);
            const int half = i & 1;
            // LDS dest: wave-uniform base, HW adds lane*16 -> phys chunk half*64+lane
            float* ldst = &Atile[row * 512 + half * 256];
            // logical k4 = phys k4 ^ (row&7)  (XOR swizzle via global src)
            const int lk4 = (half * 64 + lane) ^ (row & 7);
            gload_lds16(xb + row * 512 + lk4 * 4, ldst);
        }
    }
    __syncthreads();

    // ---- K-loop ----
    const int colbase = wave * 64;
    const unsigned short* bp = Mfrag + ((size_t)((colbase >> 4) * 64) + lane) * 8;
    const int s = l15 & 7;            // row&7 for both mi (rows mi*16+l15)

    f32x4_t acc[2][4];
#pragma unroll
    for (int a = 0; a < 2; ++a)
#pragma unroll
        for (int b = 0; b < 4; ++b)
            acc[a][b] = (f32x4_t){0.f, 0.f, 0.f, 0.f};

#pragma unroll 4
    for (int ks = 0; ks < 16; ++ks) {
        bf16x8_t bfr[4];
#pragma unroll
        for (int ni = 0; ni < 4; ++ni)
            bfr[ni] = *reinterpret_cast<const bf16x8_t*>(bp + ks * 16384 + ni * 512);

        bf16x8_t a[2];
#pragma unroll
        for (int mi = 0; mi < 2; ++mi) {
            const int row = mi * 16 + l15;
            const int pl  = ks * 8 + ((g * 2) ^ s);
            const int ph  = ks * 8 + ((g * 2 + 1) ^ s);
            f32x4_t lo = *reinterpret_cast<const f32x4_t*>(&Atile[row * 512 + pl * 4]);
            f32x4_t hi = *reinterpret_cast<const f32x4_t*>(&Atile[row * 512 + ph * 4]);
#pragma unroll
            for (int j = 0; j < 4; ++j) {
                a[mi][j]     = f2bfs(lo[j]);
                a[mi][j + 4] = f2bfs(hi[j]);
            }
        }
#pragma unroll
        for (int mi = 0; mi < 2; ++mi)
#pragma unroll
            for (int ni = 0; ni < 4; ++ni)
                acc[mi][ni] = __builtin_amdgcn_mfma_f32_16x16x32_bf16(
                    a[mi], bfr[ni], acc[mi][ni], 0, 0, 0);
    }

    __syncthreads();   // all waves done reading Atile

    // ---- Epilogue: per-wave transpose through LDS, then 256B NT stores ----
    // scratch: 32 rows x 64 cols f32 per wave (8 KB), reusing Atile
    float* scr = Atile + wave * 2048;
    const float b_lo = bias[l15];
    const float b_hi = bias[16 + l15];

#pragma unroll
    for (int mi = 0; mi < 2; ++mi)
#pragma unroll
        for (int ni = 0; ni < 4; ++ni) {
            const float bb = (ni & 1) ? b_hi : b_lo;
#pragma unroll
            for (int r = 0; r < 4; ++r)
                scr[(mi * 16 + g * 4 + r) * 64 + ni * 16 + l15] = acc[mi][ni][r] + bb;
        }

#pragma unroll
    for (int it = 0; it < 8; ++it) {
        const int flat = it * 64 + lane;       // 0..511
        const int row  = flat >> 4;            // 0..31
        const int c4   = flat & 15;
        f32x4_t v = *reinterpret_cast<const f32x4_t*>(&scr[row * 64 + c4 * 4]);
        float* yp = Y + (rowbase + row) * 512 + colbase + c4 * 4;
        __builtin_nontemporal_store(v, reinterpret_cast<f32x4_t*>(yp));
    }
}

extern "C" void kernel_launch(void* const* d_in, const int* in_sizes, int n_in,
                              void* d_out, int out_size, void* d_ws, size_t ws_size,
                              hipStream_t stream) {
    const float* x     = (const float*)d_in[0];
    const float* basis = (const float*)d_in[1];
    const float* adj   = (const float*)d_in[2];
    const float* e     = (const float*)d_in[3];
    const float* We    = (const float*)d_in[4];
    const float* W2    = (const float*)d_in[5];
    const float* W3    = (const float*)d_in[6];
    const float* bias  = (const float*)d_in[7];

    unsigned short* Mfrag = (unsigned short*)d_ws;  // 512 KB needed
    if (ws_size < 512u * 512u * 2u) return;

    const int Bsz = in_sizes[0] / 512;              // 131072
    build_M_kernel<<<512, 512, 0, stream>>>(basis, adj, e, We, W2, W3, Mfrag);
    gemm_kernel<<<Bsz / 32, 512, 0, stream>>>(x, Mfrag, bias, (float*)d_out);
}